// Round 1
// baseline (152.011 us; speedup 1.0000x reference)
//
#include <hip/hip_runtime.h>
#include <math.h>

#define BATCH 8
#define HW_N 409600          // 640*640
#define NCH 4
#define NSEG 9

// K1 per-batch accumulator layout
#define N_K1 59
#define I_AK   0
#define I_BK   1
#define I_CK   2
#define I_POS  3
#define I_NEG  4
#define I_CNTK 5             // +s (9)
#define I_CNTT 14            // +s (9)
#define I_SUMK 23            // +s*4+c (36)

// K5 per-batch accumulator layout: 0=at 1=bt 2=ct, 3+s = sum_l[s]
#define N_K5 12

#define HIST_BINS 65536
#define HIST_BYTES ((size_t)BATCH * HIST_BINS * 4)

__device__ __forceinline__ unsigned f2key(float x) {
    unsigned u = __float_as_uint(x);
    return (u & 0x80000000u) ? ~u : (u | 0x80000000u);
}
__device__ __forceinline__ float key2f(unsigned k) {
    unsigned u = (k & 0x80000000u) ? (k & 0x7fffffffu) : ~k;
    return __uint_as_float(u);
}
__device__ __forceinline__ float wred64(float v) {
#pragma unroll
    for (int o = 32; o > 0; o >>= 1) v += __shfl_xor(v, o, 64);
    return v;
}

// ---------------------------------------------------------------------------
// K1: main per-pixel reduce: kernel-dice sums, pos/neg counts, hi-16 histogram
// of negative logits, segment sums (cnt_k, cnt_t, sum_k over C).
// ---------------------------------------------------------------------------
__global__ __launch_bounds__(256)
void k1_main(const float* __restrict__ Tl, const float* __restrict__ Kl,
             const float* __restrict__ Fv, const float* __restrict__ Gt,
             const float* __restrict__ Gk, const float* __restrict__ Tm,
             const int* __restrict__ Ltk, const int* __restrict__ Lkk,
             unsigned* __restrict__ hist, float* __restrict__ k1s) {
    const int b = blockIdx.y;
    const long base = (long)b * HW_N;
    const long f0 = (long)b * NCH * HW_N;
    unsigned* hb = hist + (size_t)b * HIST_BINS;

    float r[N_K1];
#pragma unroll
    for (int j = 0; j < N_K1; j++) r[j] = 0.f;

    for (int i = blockIdx.x * blockDim.x + threadIdx.x; i < HW_N;
         i += blockDim.x * gridDim.x) {
        float tl = Tl[base + i], kl = Kl[base + i];
        float gt = Gt[base + i], gk = Gk[base + i], m = Tm[base + i];
        int ltk_v = Ltk[base + i], lkk_v = Lkk[base + i];
        float F0 = Fv[f0 + i];
        float F1 = Fv[f0 + HW_N + i];
        float F2 = Fv[f0 + 2 * HW_N + i];
        float F3 = Fv[f0 + 3 * HW_N + i];

        bool tm = m > 0.5f;
        bool selt = tl > 0.0f;          // sigmoid(x) > 0.5  <=>  x > 0
        bool selk = kl > 0.0f;
        float km = (selt && tm) ? 1.f : 0.f;

        float pk = 1.f / (1.f + expf(-kl));
        r[I_AK] += pk * gk * km;
        r[I_BK] += pk * pk * km;
        r[I_CK] += gk * gk * km;

        bool pos = gt > 0.5f;
        r[I_POS] += (pos && tm) ? 1.f : 0.f;
        if (!pos) {
            r[I_NEG] += 1.f;
            unsigned key = f2key(tl);
            atomicAdd(&hb[key >> 16], 1u);
        }

        int lt = (selt && tm) ? ltk_v : 0;
        int lk = (selk && tm) ? lkk_v : 0;
#pragma unroll
        for (int s = 0; s < NSEG; s++) {
            bool ek = (lk == s), et = (lt == s);
            r[I_CNTK + s] += ek ? 1.f : 0.f;
            r[I_CNTT + s] += et ? 1.f : 0.f;
            r[I_SUMK + s * 4 + 0] += ek ? F0 : 0.f;
            r[I_SUMK + s * 4 + 1] += ek ? F1 : 0.f;
            r[I_SUMK + s * 4 + 2] += ek ? F2 : 0.f;
            r[I_SUMK + s * 4 + 3] += ek ? F3 : 0.f;
        }
    }

#pragma unroll
    for (int j = 0; j < N_K1; j++) r[j] = wred64(r[j]);

    __shared__ float bacc[N_K1];
    for (int j = threadIdx.x; j < N_K1; j += blockDim.x) bacc[j] = 0.f;
    __syncthreads();
    if ((threadIdx.x & 63) == 0) {
#pragma unroll
        for (int j = 0; j < N_K1; j++) atomicAdd(&bacc[j], r[j]);
    }
    __syncthreads();
    for (int j = threadIdx.x; j < N_K1; j += blockDim.x)
        atomicAdd(&k1s[b * N_K1 + j], bacc[j]);
}

// ---------------------------------------------------------------------------
// K2: per-batch: k = min(3*pos, neg); scan hi histogram from the top to find
// the bin containing the k-th largest negative logit.
// ---------------------------------------------------------------------------
__global__ __launch_bounds__(256)
void k2_selhi(const unsigned* __restrict__ hist, const float* __restrict__ k1s,
              float* thr, unsigned* kval, unsigned* binhi, unsigned* cntb,
              unsigned* fb) {
    const int b = blockIdx.x;
    const int t = threadIdx.x;
    const unsigned* hb = hist + (size_t)b * HIST_BINS;

    unsigned pos = (unsigned)(k1s[b * N_K1 + I_POS] + 0.5f);
    unsigned neg = (unsigned)(k1s[b * N_K1 + I_NEG] + 0.5f);
    unsigned k = min(3u * pos, neg);
    if (t == 0) kval[b] = k;
    if (pos == 0u || k == 0u) {
        if (t == 0) { fb[b] = 1u; thr[b] = -INFINITY; }
        return;
    }
    if (t == 0) fb[b] = 0u;

    const int hi_start = 65535 - t * 256;   // this thread's 256-bin chunk (descending)
    unsigned csum = 0;
    for (int i = 0; i < 256; i++) csum += hb[hi_start - i];

    __shared__ unsigned pref[256];
    pref[t] = csum;
    __syncthreads();
    for (int o = 1; o < 256; o <<= 1) {
        unsigned v = (t >= o) ? pref[t - o] : 0u;
        __syncthreads();
        pref[t] += v;
        __syncthreads();
    }
    unsigned incl = pref[t];
    unsigned excl = incl - csum;
    if (excl < k && incl >= k) {
        unsigned cum = excl;
        for (int i = 0; i < 256; i++) {
            unsigned h = hb[hi_start - i];
            cum += h;
            if (cum >= k) {
                binhi[b] = (unsigned)(hi_start - i);
                cntb[b] = cum - h;
                break;
            }
        }
    }
}

// ---------------------------------------------------------------------------
// K3: low-16 histogram for pixels whose key falls in the selected hi bin.
// ---------------------------------------------------------------------------
__global__ __launch_bounds__(256)
void k3_histlo(const float* __restrict__ Tl, const float* __restrict__ Gt,
               const unsigned* __restrict__ binhi, const unsigned* __restrict__ fb,
               unsigned* __restrict__ hist) {
    const int b = blockIdx.y;
    if (fb[b]) return;
    const unsigned target = binhi[b];
    const long base = (long)b * HW_N;
    unsigned* hb = hist + (size_t)b * HIST_BINS;
    for (int i = blockIdx.x * blockDim.x + threadIdx.x; i < HW_N;
         i += blockDim.x * gridDim.x) {
        float gt = Gt[base + i];
        if (gt > 0.5f) continue;
        unsigned key = f2key(Tl[base + i]);
        if ((key >> 16) == target) atomicAdd(&hb[key & 0xFFFFu], 1u);
    }
}

// ---------------------------------------------------------------------------
// K4: per-batch: find exact threshold key within the hi bin.
// ---------------------------------------------------------------------------
__global__ __launch_bounds__(256)
void k4_sello(const unsigned* __restrict__ hist, const unsigned* __restrict__ kval,
              const unsigned* __restrict__ binhi, const unsigned* __restrict__ cntb,
              const unsigned* __restrict__ fb, float* thr) {
    const int b = blockIdx.x;
    if (fb[b]) return;
    const int t = threadIdx.x;
    const unsigned* hb = hist + (size_t)b * HIST_BINS;
    unsigned j = kval[b] - cntb[b];     // j-th largest within the bin, j >= 1

    const int hi_start = 65535 - t * 256;
    unsigned csum = 0;
    for (int i = 0; i < 256; i++) csum += hb[hi_start - i];

    __shared__ unsigned pref[256];
    pref[t] = csum;
    __syncthreads();
    for (int o = 1; o < 256; o <<= 1) {
        unsigned v = (t >= o) ? pref[t - o] : 0u;
        __syncthreads();
        pref[t] += v;
        __syncthreads();
    }
    unsigned incl = pref[t];
    unsigned excl = incl - csum;
    if (excl < j && incl >= j) {
        unsigned cum = excl;
        for (int i = 0; i < 256; i++) {
            unsigned h = hb[hi_start - i];
            cum += h;
            if (cum >= j) {
                unsigned lo = (unsigned)(hi_start - i);
                thr[b] = key2f((binhi[b] << 16) | lo);
                break;
            }
        }
    }
}

// ---------------------------------------------------------------------------
// K5: text dice sums with OHEM mask + aggregation-loss segment sums.
// ---------------------------------------------------------------------------
__global__ __launch_bounds__(256)
void k5_textagg(const float* __restrict__ Tl, const float* __restrict__ Gt,
                const float* __restrict__ Tm, const int* __restrict__ Ltk,
                const float* __restrict__ Fv, const float* __restrict__ k1s,
                const float* __restrict__ thr, float* __restrict__ k5s) {
    const int b = blockIdx.y;
    __shared__ float Km[NSEG * NCH];
    if (threadIdx.x < NSEG * NCH) {
        int s = threadIdx.x >> 2, c = threadIdx.x & 3;
        Km[threadIdx.x] = k1s[b * N_K1 + I_SUMK + s * 4 + c] /
                          fmaxf(k1s[b * N_K1 + I_CNTK + s], 1.f);
    }
    __syncthreads();
    const float thr_b = thr[b];
    const long base = (long)b * HW_N;
    const long f0 = (long)b * NCH * HW_N;

    float r[N_K5];
#pragma unroll
    for (int j = 0; j < N_K5; j++) r[j] = 0.f;

    for (int i = blockIdx.x * blockDim.x + threadIdx.x; i < HW_N;
         i += blockDim.x * gridDim.x) {
        float tl = Tl[base + i], gt = Gt[base + i], m = Tm[base + i];
        int ltk_v = Ltk[base + i];
        float F0 = Fv[f0 + i];
        float F1 = Fv[f0 + HW_N + i];
        float F2 = Fv[f0 + 2 * HW_N + i];
        float F3 = Fv[f0 + 3 * HW_N + i];

        bool tm = m > 0.5f;
        bool pos = gt > 0.5f;
        float om = (((tl >= thr_b) || pos) && tm) ? 1.f : 0.f;
        float pt = 1.f / (1.f + expf(-tl));
        r[0] += pt * gt * om;
        r[1] += pt * pt * om;
        r[2] += gt * gt * om;

        int lt = (tl > 0.f && tm) ? ltk_v : 0;
        if (lt > 0) {
            float d0 = F0 - Km[lt * 4 + 0];
            float d1 = F1 - Km[lt * 4 + 1];
            float d2 = F2 - Km[lt * 4 + 2];
            float d3 = F3 - Km[lt * 4 + 3];
            float d = sqrtf(d0 * d0 + d1 * d1 + d2 * d2 + d3 * d3);
            float tt = fmaxf(d - 0.5f, 0.f);
            float pl = logf(tt * tt + 1.f);
#pragma unroll
            for (int s = 1; s < NSEG; s++) r[3 + s] += (lt == s) ? pl : 0.f;
        }
    }

#pragma unroll
    for (int j = 0; j < N_K5; j++) r[j] = wred64(r[j]);

    __shared__ float bacc[N_K5];
    if (threadIdx.x < N_K5) bacc[threadIdx.x] = 0.f;
    __syncthreads();
    if ((threadIdx.x & 63) == 0) {
#pragma unroll
        for (int j = 0; j < N_K5; j++) atomicAdd(&bacc[j], r[j]);
    }
    __syncthreads();
    if (threadIdx.x < N_K5)
        atomicAdd(&k5s[b * N_K5 + threadIdx.x], bacc[threadIdx.x]);
}

// ---------------------------------------------------------------------------
// K6: final combine -> scalar loss. One block of 512 (wave w = batch w).
// ---------------------------------------------------------------------------
__global__ __launch_bounds__(512)
void k6_final(const float* __restrict__ k1s, const float* __restrict__ k5s,
              float* __restrict__ out) {
    const int tid = threadIdx.x;
    const int b = tid >> 6, lane = tid & 63;
    __shared__ float Km[BATCH][NSEG][NCH];
    __shared__ float laS[BATCH], ldS[BATCH];

    if (tid < BATCH * NSEG * NCH) {
        int bb = tid / (NSEG * NCH);
        int rem = tid % (NSEG * NCH);
        int s = rem >> 2, c = rem & 3;
        Km[bb][s][c] = k1s[bb * N_K1 + I_SUMK + s * 4 + c] /
                       fmaxf(k1s[bb * N_K1 + I_CNTK + s], 1.f);
    }
    __syncthreads();

    const float* s1 = k1s + b * N_K1;
    const float* s5 = k5s + b * N_K5;

    // aggregation loss: lanes 1..8 handle instances
    float aggs = 0.f, aggc = 0.f;
    if (lane > 0 && lane < NSEG) {
        float ct = s1[I_CNTT + lane], ck = s1[I_CNTK + lane];
        if (ct > 0.f && ck > 0.f) {
            aggs = s5[3 + lane] / fmaxf(ct, 1.f);
            aggc = 1.f;
        }
    }
    // discrimination loss: 81 pairs across lanes
    float diss = 0.f, disc = 0.f;
    for (int p = lane; p < NSEG * NSEG; p += 64) {
        int i = p / NSEG, j = p % NSEG;
        if (i != j && i > 0 && j > 0 && s1[I_CNTK + i] > 0.f &&
            s1[I_CNTK + j] > 0.f) {
            float d2 = 0.f;
#pragma unroll
            for (int c = 0; c < NCH; c++) {
                float df = Km[b][i][c] - Km[b][j][c];
                d2 += df * df;
            }
            float kd = sqrtf(d2);
            float t = fmaxf(3.0f - kd, 0.f);
            diss += logf(t * t + 1.f);
            disc += 1.f;
        }
    }
    aggs = wred64(aggs);
    aggc = wred64(aggc);
    diss = wred64(diss);
    disc = wred64(disc);
    if (lane == 0) {
        laS[b] = aggs / fmaxf(aggc, 1.f);
        ldS[b] = diss / fmaxf(disc, 1.f);
    }
    __syncthreads();

    if (tid == 0) {
        float Ltx = 0.f, Lk = 0.f, La = 0.f, Ld = 0.f;
        for (int bb = 0; bb < BATCH; bb++) {
            const float* a1 = k1s + bb * N_K1;
            const float* a5 = k5s + bb * N_K5;
            Lk += 1.f - 2.f * a1[I_AK] / ((a1[I_BK] + 1e-6f) + (a1[I_CK] + 1e-6f));
            Ltx += 1.f - 2.f * a5[0] / ((a5[1] + 1e-6f) + (a5[2] + 1e-6f));
            La += laS[bb];
            Ld += ldS[bb];
        }
        out[0] = Ltx / BATCH + 0.5f * (Lk / BATCH) + 0.25f * (La / BATCH + Ld / BATCH);
    }
}

// ---------------------------------------------------------------------------
extern "C" void kernel_launch(void* const* d_in, const int* in_sizes, int n_in,
                              void* d_out, int out_size, void* d_ws, size_t ws_size,
                              hipStream_t stream) {
    (void)in_sizes; (void)n_in; (void)out_size; (void)ws_size;
    const float* Tl = (const float*)d_in[0];   // pre_text_logits
    const float* Kl = (const float*)d_in[1];   // pre_kernel_logits
    const float* Fv = (const float*)d_in[2];   // similarity_vector [B,C,H,W]
    const float* Gt = (const float*)d_in[3];   // gt_text
    const float* Gk = (const float*)d_in[4];   // gt_kernel
    const float* Tm = (const float*)d_in[5];   // train_mask
    const int* Ltk = (const int*)d_in[6];      // gt_text_key
    const int* Lkk = (const int*)d_in[7];      // gt_kernel_key
    float* out = (float*)d_out;

    unsigned char* wsb = (unsigned char*)d_ws;
    unsigned* hist = (unsigned*)wsb;                       // B*65536 u32
    float* k1s = (float*)(wsb + HIST_BYTES);               // B*59 f32
    float* k5s = k1s + BATCH * N_K1;                       // B*12 f32
    float* thr = k5s + BATCH * N_K5;                       // B f32
    unsigned* kval = (unsigned*)(thr + BATCH);             // B u32
    unsigned* binhi = kval + BATCH;
    unsigned* cntb = binhi + BATCH;
    unsigned* fb = cntb + BATCH;

    size_t zero_bytes = HIST_BYTES +
                        (size_t)(BATCH * (N_K1 + N_K5 + 1)) * 4 +
                        (size_t)BATCH * 4 * 4;
    hipMemsetAsync(d_ws, 0, zero_bytes, stream);

    dim3 g(128, BATCH);
    k1_main<<<g, 256, 0, stream>>>(Tl, Kl, Fv, Gt, Gk, Tm, Ltk, Lkk, hist, k1s);
    k2_selhi<<<BATCH, 256, 0, stream>>>(hist, k1s, thr, kval, binhi, cntb, fb);
    hipMemsetAsync(hist, 0, HIST_BYTES, stream);
    k3_histlo<<<g, 256, 0, stream>>>(Tl, Gt, binhi, fb, hist);
    k4_sello<<<BATCH, 256, 0, stream>>>(hist, kval, binhi, cntb, fb, thr);
    k5_textagg<<<g, 256, 0, stream>>>(Tl, Gt, Tm, Ltk, Fv, k1s, thr, k5s);
    k6_final<<<1, 512, 0, stream>>>(k1s, k5s, out);
}